// Round 8
// baseline (2273.604 us; speedup 1.0000x reference)
//
#include <hip/hip_runtime.h>
#include <cstdint>
#include <cstddef>

#define T_DIM 8
#define V_DIM 10000
#define E_DIM 100000
#define VS (V_DIM * 256)

typedef __attribute__((ext_vector_type(8))) short short8;
typedef __attribute__((ext_vector_type(4))) float floatx4;

__device__ __forceinline__ unsigned int f2bf(float f) {
    union { float f; unsigned int u; } v; v.f = f;
    unsigned int u = v.u;
    u = u + 0x7FFFu + ((u >> 16) & 1u);   // RNE
    return u >> 16;
}
__device__ __forceinline__ float bf2f(unsigned int s) {
    union { unsigned int u; float f; } v; v.u = s << 16;
    return v.f;
}
__device__ __forceinline__ short8 relu8(short8 x) {
    const short8 z = {0,0,0,0,0,0,0,0};
    return __builtin_elementwise_max(x, z);   // v_pk_max_i16: bf16 relu on bit pattern
}
union PK { uint4 u; short8 s; };

// ---- pack fp32 weight [K,Nw] into MFMA B-fragment order inside a concat buffer
__global__ void pack_b_kernel(const float* __restrict__ w, unsigned short* __restrict__ out,
                              int K, int Nw, int NTN_tot, int nt_off) {
    int tid = blockIdx.x * blockDim.x + threadIdx.x;
    int total = (K >> 5) * (Nw >> 4) * 64;
    if (tid >= total) return;
    int lane = tid & 63;
    int f = tid >> 6;
    int ntn_w = Nw >> 4;
    int nt = f % ntn_w;
    int kt = f / ntn_w;
    int kbase = kt * 32 + ((lane >> 4) << 3);
    int n = nt * 16 + (lane & 15);
    unsigned int vals[8];
#pragma unroll
    for (int j = 0; j < 8; ++j)
        vals[j] = f2bf(w[(size_t)(kbase + j) * Nw + n]);
    uint4 pk;
    pk.x = vals[0] | (vals[1] << 16);
    pk.y = vals[2] | (vals[3] << 16);
    pk.z = vals[4] | (vals[5] << 16);
    pk.w = vals[6] | (vals[7] << 16);
    size_t fo = (size_t)kt * NTN_tot + nt_off + nt;
    *(uint4*)(out + (fo * 64 + lane) * 8) = pk;
}

// ---- token mixer ----
__global__ void token_mix_kernel(const float* __restrict__ xs, const float* __restrict__ w_pre,
                                 const float* __restrict__ b_pre, unsigned short* __restrict__ ob) {
    const int S = V_DIM * 128;
    int tid = blockIdx.x * blockDim.x + threadIdx.x;
    if (tid >= T_DIM * S / 4) return;
    int e = tid * 4;
    int t = e / S;
    int c = e & 127;
    floatx4 xm = {0.f,0.f,0.f,0.f}, xp = {0.f,0.f,0.f,0.f};
    floatx4 x0 = *(const floatx4*)(xs + e);
    if (t > 0)          xm = *(const floatx4*)(xs + e - S);
    if (t < T_DIM - 1)  xp = *(const floatx4*)(xs + e + S);
    uint2 p; unsigned int b[4];
#pragma unroll
    for (int j = 0; j < 4; ++j) {
        int cc = c + j;
        float r = xm[j]*w_pre[cc*3+0] + x0[j]*w_pre[cc*3+1] + xp[j]*w_pre[cc*3+2] + b_pre[cc];
        b[j] = f2bf(r);
    }
    p.x = b[0] | (b[1] << 16);
    p.y = b[2] | (b[3] << 16);
    *(uint2*)(ob + e) = p;
}

// ---- P0[d][k] = B0[k]*lam0^d ; P1[d][k] = B1[k]*lam1^d  (d = 0..7) ----
__global__ void lamP_kernel(const float* __restrict__ a0, const float* __restrict__ a1,
                            const float* __restrict__ B0, const float* __restrict__ B1,
                            float* __restrict__ P0, float* __restrict__ P1) {
    int i = blockIdx.x * blockDim.x + threadIdx.x;
    if (i >= 4096) return;
    float l0 = expf(-expf(a0[i]));
    float l1 = expf(-expf(a1[i]));
    float p0 = B0[i], p1 = B1[i];
#pragma unroll
    for (int d = 0; d < 8; ++d) {
        P0[d * 4096 + i] = p0;
        P1[d * 4096 + i] = p1;
        p0 *= l0; p1 *= l1;
    }
}

// ---- bias concat: [b_sage | 0 | b_res] per layer (region order self|neigh|res) ----
__global__ void bias_cat_kernel(const float* __restrict__ br0, const float* __restrict__ bs0,
                                const float* __restrict__ br1, const float* __restrict__ bs1,
                                float* __restrict__ bcat0, float* __restrict__ bcat1) {
    int i = blockIdx.x * blockDim.x + threadIdx.x;
    if (i >= 768) return;
    bcat0[i] = (i < 256) ? bs0[i] : (i < 512 ? 0.f : br0[i - 512]);
    bcat1[i] = (i < 256) ? bs1[i] : (i < 512 ? 0.f : br1[i - 512]);
}

// ================= CSR build =================
__global__ void deg_kernel(const int* __restrict__ ei, int* __restrict__ deg_cnt) {
    int tid = blockIdx.x * blockDim.x + threadIdx.x;
    if (tid >= T_DIM * E_DIM) return;
    int t = tid / E_DIM;
    int e = tid - t * E_DIM;
    int dst = ei[(size_t)t * 2 * E_DIM + E_DIM + e];
    if ((unsigned)dst < V_DIM) atomicAdd(deg_cnt + t * V_DIM + dst, 1);
}

__global__ void invdeg_kernel(const int* __restrict__ deg_cnt, float* __restrict__ inv) {
    int tid = blockIdx.x * blockDim.x + threadIdx.x;
    if (tid >= T_DIM * V_DIM) return;
    inv[tid] = 1.0f / (float)max(deg_cnt[tid], 1);
}

__global__ __launch_bounds__(1024)
void scan_kernel(const int* __restrict__ deg_cnt, int* __restrict__ rowptr) {
    __shared__ int sums[1024];
    int t = blockIdx.x;
    const int* d = deg_cnt + t * V_DIM;
    int* rp = rowptr + t * (V_DIM + 1);
    int tid = threadIdx.x;
    int base = tid * 10;
    int loc[10]; int s = 0;
#pragma unroll
    for (int j = 0; j < 10; ++j) {
        int v = base + j;
        int x = (v < V_DIM) ? d[v] : 0;
        loc[j] = s; s += x;
    }
    sums[tid] = s;
    __syncthreads();
    for (int o = 1; o < 1024; o <<= 1) {
        int v = (tid >= o) ? sums[tid - o] : 0;
        __syncthreads();
        sums[tid] += v;
        __syncthreads();
    }
    int prev = (tid == 0) ? 0 : sums[tid - 1];
#pragma unroll
    for (int j = 0; j < 10; ++j) {
        int v = base + j;
        if (v < V_DIM) rp[v] = prev + loc[j];
    }
    if (tid == 1023) rp[V_DIM] = sums[1023];
}

__global__ void fill_kernel(const int* __restrict__ ei, const int* __restrict__ rowptr,
                            int* __restrict__ fill_cnt, int* __restrict__ srcs) {
    int tid = blockIdx.x * blockDim.x + threadIdx.x;
    if (tid >= T_DIM * E_DIM) return;
    int t = tid / E_DIM;
    int e = tid - t * E_DIM;
    const int* eit = ei + (size_t)t * 2 * E_DIM;
    int src = eit[e];
    int dst = eit[E_DIM + e];
    if ((unsigned)src >= V_DIM || (unsigned)dst >= V_DIM) return;
    int pos = rowptr[t * (V_DIM + 1) + dst] + atomicAdd(fill_cnt + t * V_DIM + dst, 1);
    srcs[(size_t)t * E_DIM + pos] = src;
}

// ---- gather + slot-pack: h = hb + (sum xn[src])*invdeg, written to hpack[v][c][slot]
__global__ void gather_pack_kernel(const unsigned short* __restrict__ xn, const int* __restrict__ srcs,
                                   const int* __restrict__ rowptr, const float* __restrict__ invdeg,
                                   const unsigned short* __restrict__ hb,
                                   unsigned short* __restrict__ hpack, int slot) {
    int gw = (blockIdx.x * blockDim.x + threadIdx.x) >> 6;
    int lane = threadIdx.x & 63;
    if (gw >= V_DIM) return;
    int beg = rowptr[gw], end = rowptr[gw + 1];
    float a0 = 0.f, a1 = 0.f, a2 = 0.f, a3 = 0.f;
    for (int i = beg; i < end; ++i) {
        int s = srcs[i];
        uint2 p = *(const uint2*)(xn + (size_t)s * 256 + lane * 4);
        a0 += bf2f(p.x & 0xffffu);
        a1 += bf2f(p.x >> 16);
        a2 += bf2f(p.y & 0xffffu);
        a3 += bf2f(p.y >> 16);
    }
    float inv = invdeg[gw];
    uint2 h = *(const uint2*)(hb + (size_t)gw * 256 + lane * 4);
    a0 = a0 * inv + bf2f(h.x & 0xffffu);
    a1 = a1 * inv + bf2f(h.x >> 16);
    a2 = a2 * inv + bf2f(h.y & 0xffffu);
    a3 = a3 * inv + bf2f(h.y >> 16);
    unsigned short* op = hpack + (size_t)gw * 2048 + (size_t)(lane * 4) * 8 + slot;
    op[0]  = (unsigned short)f2bf(a0);
    op[8]  = (unsigned short)f2bf(a1);
    op[16] = (unsigned short)f2bf(a2);
    op[24] = (unsigned short)f2bf(a3);
}

// ---- cat GEMM: x(t) @ [w_self|w_neigh|w_res]; region 0->bf16 d_self, 1->bf16 d_xn, 2->f32 d_xsr
template<int KT>
__global__ __launch_bounds__(256, 4)
void gemm_cat3_kernel(const unsigned short* __restrict__ A, const unsigned short* __restrict__ Bp,
                      const float* __restrict__ bias, unsigned short* __restrict__ d_self,
                      unsigned short* __restrict__ d_xn, float* __restrict__ d_xsr, int M) {
    const int w = threadIdx.x >> 6, lane = threadIdx.x & 63;
    const int quad = lane >> 4, l16 = lane & 15;
    const int region = blockIdx.x;
    const int m0 = blockIdx.y * 64;
    constexpr int K = KT * 32;
    floatx4 acc[4][4];
#pragma unroll
    for (int a = 0; a < 4; ++a)
#pragma unroll
        for (int b = 0; b < 4; ++b) acc[a][b] = (floatx4){0.f,0.f,0.f,0.f};
    const unsigned short* arow[4];
#pragma unroll
    for (int mi = 0; mi < 4; ++mi) {
        int r = m0 + mi * 16 + l16;
        if (r > M - 1) r = M - 1;
        arow[mi] = A + (size_t)r * K + quad * 8;
    }
    const unsigned short* bptr = Bp + ((size_t)(region * 16 + w * 4) * 64 + lane) * 8;
#pragma unroll
    for (int kt = 0; kt < KT; ++kt) {
        short8 bfr[4];
#pragma unroll
        for (int i = 0; i < 4; ++i) bfr[i] = *(const short8*)(bptr + i * 512);
        short8 af[4];
#pragma unroll
        for (int mi = 0; mi < 4; ++mi) af[mi] = *(const short8*)(arow[mi]);
#pragma unroll
        for (int mi = 0; mi < 4; ++mi)
#pragma unroll
            for (int i = 0; i < 4; ++i)
                acc[mi][i] = __builtin_amdgcn_mfma_f32_16x16x32_bf16(af[mi], bfr[i], acc[mi][i], 0, 0, 0);
        bptr += 48 * 512;
#pragma unroll
        for (int mi = 0; mi < 4; ++mi) arow[mi] += 32;
    }
#pragma unroll
    for (int mi = 0; mi < 4; ++mi) {
        int rbase = m0 + mi * 16 + quad * 4;
#pragma unroll
        for (int i = 0; i < 4; ++i) {
            int lcol = w * 64 + i * 16 + l16;
            float b = bias[region * 256 + lcol];
#pragma unroll
            for (int rr = 0; rr < 4; ++rr) {
                int row = rbase + rr;
                if (row < M) {
                    float v = acc[mi][i][rr] + b;
                    size_t off = (size_t)row * 256 + lcol;
                    if (region == 0) d_self[off] = (unsigned short)f2bf(v);
                    else if (region == 1) d_xn[off] = (unsigned short)f2bf(v);
                    else d_xsr[off] = v;
                }
            }
        }
    }
}

// ---- closed-form state build: stateR[v][k] = relu(bf16(sum_{tau<=TT} P[TT-tau][k]*h[tau][v][k>>4]))
// one thread per (v, c): 16B hpack load -> 16 outputs (32B coalesced store).
template<int TT>
__global__ __launch_bounds__(256)
void state_build_kernel(const unsigned short* __restrict__ hp,  // [V][256][8]
                        const float* __restrict__ P,            // [8][4096]
                        unsigned short* __restrict__ st) {      // [V][4096] relu'd bf16
    int tid = blockIdx.x * blockDim.x + threadIdx.x;
    if (tid >= V_DIM * 256) return;
    int v = tid >> 8;
    int c = tid & 255;
    PK h8;
    h8.u = *(const uint4*)(hp + (size_t)v * 2048 + c * 8);
    float hv[TT + 1];
#pragma unroll
    for (int tau = 0; tau <= TT; ++tau)
        hv[tau] = bf2f((unsigned int)(unsigned short)h8.s[tau]);
    float sv[16];
#pragma unroll
    for (int j = 0; j < 16; ++j) sv[j] = 0.f;
#pragma unroll
    for (int tau = 0; tau <= TT; ++tau) {
        const float* Pd = P + (size_t)(TT - tau) * 4096 + c * 16;
#pragma unroll
        for (int g = 0; g < 4; ++g) {
            floatx4 p = *(const floatx4*)(Pd + g * 4);
#pragma unroll
            for (int j = 0; j < 4; ++j) sv[g * 4 + j] += hv[tau] * p[j];
        }
    }
    PK o0, o1;
    o0.u.x = f2bf(sv[0])  | (f2bf(sv[1])  << 16);
    o0.u.y = f2bf(sv[2])  | (f2bf(sv[3])  << 16);
    o0.u.z = f2bf(sv[4])  | (f2bf(sv[5])  << 16);
    o0.u.w = f2bf(sv[6])  | (f2bf(sv[7])  << 16);
    o1.u.x = f2bf(sv[8])  | (f2bf(sv[9])  << 16);
    o1.u.y = f2bf(sv[10]) | (f2bf(sv[11]) << 16);
    o1.u.z = f2bf(sv[12]) | (f2bf(sv[13]) << 16);
    o1.u.w = f2bf(sv[14]) | (f2bf(sv[15]) << 16);
    o0.s = relu8(o0.s);
    o1.s = relu8(o1.s);
    unsigned short* op = st + (size_t)v * 4096 + c * 16;
    *(uint4*)op = o0.u;
    *(uint4*)(op + 8) = o1.u;
}

// ---- split-K mix GEMM on pre-relu'd bf16 state: part[ks] = stateR_slice @ Wp_slice ----
// grid (4 splits, 157); block 64 rows x 256 cols; wave = 64 rows x 64 cols; B-frag reuse x4 m-tiles
__global__ __launch_bounds__(256)
void gemm_mixP_kernel(const unsigned short* __restrict__ A, const unsigned short* __restrict__ Bp,
                      float* __restrict__ part, int M) {
    const int w = threadIdx.x >> 6, lane = threadIdx.x & 63;
    const int quad = lane >> 4, l16 = lane & 15;
    const int ks = blockIdx.x;
    const int m0 = blockIdx.y * 64;
    floatx4 acc[4][4];
#pragma unroll
    for (int a = 0; a < 4; ++a)
#pragma unroll
        for (int b = 0; b < 4; ++b) acc[a][b] = (floatx4){0.f,0.f,0.f,0.f};
    const unsigned short* arow[4];
#pragma unroll
    for (int mi = 0; mi < 4; ++mi) {
        int r = m0 + mi * 16 + l16;
        if (r > M - 1) r = M - 1;
        arow[mi] = A + (size_t)r * 4096 + ks * 1024 + quad * 8;
    }
    const unsigned short* bptr = Bp + ((size_t)(ks * 512 + w * 4) * 64 + lane) * 8;
    for (int kt = 0; kt < 32; ++kt) {
        short8 bfr[4];
#pragma unroll
        for (int i = 0; i < 4; ++i) bfr[i] = *(const short8*)(bptr + i * 512);
        short8 af[4];
#pragma unroll
        for (int mi = 0; mi < 4; ++mi) af[mi] = *(const short8*)(arow[mi]);
#pragma unroll
        for (int mi = 0; mi < 4; ++mi)
#pragma unroll
            for (int i = 0; i < 4; ++i)
                acc[mi][i] = __builtin_amdgcn_mfma_f32_16x16x32_bf16(af[mi], bfr[i], acc[mi][i], 0, 0, 0);
        bptr += 16 * 512;
#pragma unroll
        for (int mi = 0; mi < 4; ++mi) arow[mi] += 32;
    }
#pragma unroll
    for (int mi = 0; mi < 4; ++mi) {
        int rbase = m0 + mi * 16 + quad * 4;
#pragma unroll
        for (int i = 0; i < 4; ++i) {
            int col = w * 64 + i * 16 + l16;
#pragma unroll
            for (int rr = 0; rr < 4; ++rr) {
                int row = rbase + rr;
                if (row < M)
                    part[((size_t)ks * M + row) * 256 + col] = acc[mi][i][rr];
            }
        }
    }
}

// ---- reduce 4 split-K partials + bias + resid -> bf16 ----
__global__ void reduce4_kernel(const float* __restrict__ part, const float* __restrict__ bias,
                               const float* __restrict__ resid, unsigned short* __restrict__ out, int M) {
    int tid = blockIdx.x * blockDim.x + threadIdx.x;
    if (tid >= M * 64) return;
    size_t i4 = (size_t)tid * 4;
    const size_t S = (size_t)M * 256;
    floatx4 s = *(const floatx4*)(part + i4);
    floatx4 s1 = *(const floatx4*)(part + S + i4);
    floatx4 s2 = *(const floatx4*)(part + 2 * S + i4);
    floatx4 s3 = *(const floatx4*)(part + 3 * S + i4);
    floatx4 rv = *(const floatx4*)(resid + i4);
    floatx4 bv = *(const floatx4*)(bias + (i4 & 255));
    uint2 o;
    float v0 = s[0] + s1[0] + s2[0] + s3[0] + rv[0] + bv[0];
    float v1 = s[1] + s1[1] + s2[1] + s3[1] + rv[1] + bv[1];
    float v2 = s[2] + s1[2] + s2[2] + s3[2] + rv[2] + bv[2];
    float v3 = s[3] + s1[3] + s2[3] + s3[3] + rv[3] + bv[3];
    o.x = f2bf(v0) | (f2bf(v1) << 16);
    o.y = f2bf(v2) | (f2bf(v3) << 16);
    *(uint2*)(out + i4) = o;
}

// ---- small GEMM (head): 32-row blocks, 8 waves ----
template<int NT, int NTN_TOT, bool RELU>
__global__ __launch_bounds__(512)
void gemm16_kernel(const unsigned short* __restrict__ A, const unsigned short* __restrict__ Bp,
                   const float* __restrict__ bias, float* __restrict__ outF, int M, int K) {
    const int w = threadIdx.x >> 6, lane = threadIdx.x & 63;
    const int quad = lane >> 4, l16 = lane & 15;
    const int rowgrp = w >> 2, nchunk = w & 3;
    const int m0 = blockIdx.x * 32 + rowgrp * 16;
    const int ntb = nchunk * NT;
    constexpr int Ntot = NTN_TOT * 16;
    floatx4 acc[NT];
#pragma unroll
    for (int i = 0; i < NT; ++i) acc[i] = (floatx4){0.f,0.f,0.f,0.f};
    int r = m0 + l16; if (r > M - 1) r = M - 1;
    const unsigned short* arow = A + (size_t)r * K + quad * 8;
    const int ksteps = K >> 5;
    for (int kt = 0; kt < ksteps; ++kt) {
        short8 af = *(const short8*)(arow + kt * 32);
        if (RELU) af = relu8(af);
#pragma unroll
        for (int i = 0; i < NT; ++i) {
            short8 bf = *(const short8*)(Bp + ((size_t)(kt * NTN_TOT + ntb + i) * 64 + lane) * 8);
            acc[i] = __builtin_amdgcn_mfma_f32_16x16x32_bf16(af, bf, acc[i], 0, 0, 0);
        }
    }
    const int rbase = m0 + quad * 4;
#pragma unroll
    for (int i = 0; i < NT; ++i) {
        int col = (ntb + i) * 16 + l16;
        float b = bias[col];
#pragma unroll
        for (int rr = 0; rr < 4; ++rr) {
            int row = rbase + rr;
            if (row < M)
                outF[(size_t)row * Ntot + col] = acc[i][rr] + b;
        }
    }
}

extern "C" void kernel_launch(void* const* d_in, const int* in_sizes, int n_in,
                              void* d_out, int out_size, void* d_ws, size_t ws_size,
                              hipStream_t stream) {
    const float* xs      = (const float*)d_in[0];
    const int*   ei      = (const int*)d_in[1];
    const float* w_pre   = (const float*)d_in[2];
    const float* b_pre   = (const float*)d_in[3];
    const float* w_res0  = (const float*)d_in[4];
    const float* b_res0  = (const float*)d_in[5];
    const float* w_self0 = (const float*)d_in[6];
    const float* w_neigh0= (const float*)d_in[7];
    const float* b_sage0 = (const float*)d_in[8];
    const float* a_log0  = (const float*)d_in[9];
    const float* B0      = (const float*)d_in[10];
    const float* w_mix0  = (const float*)d_in[11];
    const float* b_mix0  = (const float*)d_in[12];
    const float* w_res1  = (const float*)d_in[13];
    const float* b_res1  = (const float*)d_in[14];
    const float* w_self1 = (const float*)d_in[15];
    const float* w_neigh1= (const float*)d_in[16];
    const float* b_sage1 = (const float*)d_in[17];
    const float* a_log1  = (const float*)d_in[18];
    const float* B1      = (const float*)d_in[19];
    const float* w_mix1  = (const float*)d_in[20];
    const float* b_mix1  = (const float*)d_in[21];
    const float* w_out   = (const float*)d_in[22];
    const float* b_out   = (const float*)d_in[23];

    char* wsB = (char*)d_ws;
    size_t off = 0;
    auto alloc = [&](size_t bytes) {
        char* p = wsB + off;
        off += (bytes + 255) & ~(size_t)255;
        return p;
    };
    unsigned short* x0b   = (unsigned short*)alloc((size_t)T_DIM * V_DIM * 128 * 2);
    unsigned short* hpack0= (unsigned short*)alloc((size_t)V_DIM * 2048 * 2);   // [V][256][8] layer-0 h
    unsigned short* hpack1= (unsigned short*)alloc((size_t)V_DIM * 2048 * 2);   // [V][256][8] layer-1 h
    unsigned short* stateR= (unsigned short*)alloc((size_t)V_DIM * 4096 * 2);   // relu'd bf16 state
    unsigned short* hb_t  = (unsigned short*)alloc((size_t)VS * 2);
    unsigned short* x1b_t = (unsigned short*)alloc((size_t)VS * 2);
    unsigned short* xn_t  = (unsigned short*)alloc((size_t)VS * 2);
    float*          xsr_t = (float*)alloc((size_t)VS * 4);
    float*          part  = (float*)alloc((size_t)4 * VS * 4);
    unsigned short* out1_b= (unsigned short*)alloc((size_t)VS * 2);
    int*            deg_cnt = (int*)alloc((size_t)T_DIM * V_DIM * 4);
    float*          invdeg  = (float*)alloc((size_t)T_DIM * V_DIM * 4);
    int*            rowptr  = (int*)alloc((size_t)T_DIM * (V_DIM + 1) * 4);
    int*            fill_cnt= (int*)alloc((size_t)T_DIM * V_DIM * 4);
    int*            srcs    = (int*)alloc((size_t)T_DIM * E_DIM * 4);
    float*          P0    = (float*)alloc(8 * 4096 * 4);
    float*          P1    = (float*)alloc(8 * 4096 * 4);
    float*          bcat0 = (float*)alloc(768 * 4);
    float*          bcat1 = (float*)alloc(768 * 4);
    unsigned short* wcat0p= (unsigned short*)alloc((size_t)128 * 768 * 2);
    unsigned short* wcat1p= (unsigned short*)alloc((size_t)256 * 768 * 2);
    unsigned short* wmix0p= (unsigned short*)alloc((size_t)4096 * 256 * 2);
    unsigned short* wmix1p= (unsigned short*)alloc((size_t)4096 * 256 * 2);
    unsigned short* woutp = (unsigned short*)alloc((size_t)256 * 64 * 2);
    if (off > ws_size) return;   // fail cleanly, not a GPU fault

    auto cdiv = [](int a, int b) { return (a + b - 1) / b; };
    const int gM64 = cdiv(V_DIM, 64);    // 157
    const int gGat = cdiv(V_DIM * 64, 256);
    const int gRed = cdiv(V_DIM * 64, 256);
    const int gSB  = cdiv(V_DIM * 256, 256);  // 10000

    auto launch_sb = [&](int t, const unsigned short* hp, const float* P) {
        switch (t) {
        case 0: state_build_kernel<0><<<gSB, 256, 0, stream>>>(hp, P, stateR); break;
        case 1: state_build_kernel<1><<<gSB, 256, 0, stream>>>(hp, P, stateR); break;
        case 2: state_build_kernel<2><<<gSB, 256, 0, stream>>>(hp, P, stateR); break;
        case 3: state_build_kernel<3><<<gSB, 256, 0, stream>>>(hp, P, stateR); break;
        case 4: state_build_kernel<4><<<gSB, 256, 0, stream>>>(hp, P, stateR); break;
        case 5: state_build_kernel<5><<<gSB, 256, 0, stream>>>(hp, P, stateR); break;
        case 6: state_build_kernel<6><<<gSB, 256, 0, stream>>>(hp, P, stateR); break;
        default: state_build_kernel<7><<<gSB, 256, 0, stream>>>(hp, P, stateR); break;
        }
    };

    // ---- parameter prep ----
    lamP_kernel<<<16, 256, 0, stream>>>(a_log0, a_log1, B0, B1, P0, P1);
    bias_cat_kernel<<<3, 256, 0, stream>>>(b_res0, b_sage0, b_res1, b_sage1, bcat0, bcat1);
    // region order: [self | neigh | res]
    pack_b_kernel<<<cdiv(4*16*64, 256), 256, 0, stream>>>(w_self0,  wcat0p, 128, 256, 48, 0);
    pack_b_kernel<<<cdiv(4*16*64, 256), 256, 0, stream>>>(w_neigh0, wcat0p, 128, 256, 48, 16);
    pack_b_kernel<<<cdiv(4*16*64, 256), 256, 0, stream>>>(w_res0,   wcat0p, 128, 256, 48, 32);
    pack_b_kernel<<<cdiv(8*16*64, 256), 256, 0, stream>>>(w_self1,  wcat1p, 256, 256, 48, 0);
    pack_b_kernel<<<cdiv(8*16*64, 256), 256, 0, stream>>>(w_neigh1, wcat1p, 256, 256, 48, 16);
    pack_b_kernel<<<cdiv(8*16*64, 256), 256, 0, stream>>>(w_res1,   wcat1p, 256, 256, 48, 32);
    pack_b_kernel<<<cdiv(128*16*64, 256), 256, 0, stream>>>(w_mix0, wmix0p, 4096, 256, 16, 0);
    pack_b_kernel<<<cdiv(128*16*64, 256), 256, 0, stream>>>(w_mix1, wmix1p, 4096, 256, 16, 0);
    pack_b_kernel<<<cdiv(8*4*64, 256), 256, 0, stream>>>(w_out, woutp, 256, 64, 4, 0);

    // ---- token mixer + CSR build ----
    token_mix_kernel<<<cdiv(T_DIM*V_DIM*128/4, 256), 256, 0, stream>>>(xs, w_pre, b_pre, x0b);
    hipMemsetAsync(deg_cnt, 0, (size_t)T_DIM * V_DIM * 4, stream);
    hipMemsetAsync(fill_cnt, 0, (size_t)T_DIM * V_DIM * 4, stream);
    deg_kernel<<<cdiv(T_DIM*E_DIM, 256), 256, 0, stream>>>(ei, deg_cnt);
    scan_kernel<<<T_DIM, 1024, 0, stream>>>(deg_cnt, rowptr);
    invdeg_kernel<<<cdiv(T_DIM*V_DIM, 256), 256, 0, stream>>>(deg_cnt, invdeg);
    fill_kernel<<<cdiv(T_DIM*E_DIM, 256), 256, 0, stream>>>(ei, rowptr, fill_cnt, srcs);

    // ================= main loop over t =================
    for (int t = 0; t < T_DIM; ++t) {
        // ---- layer 0 ----
        gemm_cat3_kernel<4><<<dim3(3, gM64), 256, 0, stream>>>(
            x0b + (size_t)t * V_DIM * 128, wcat0p, bcat0, hb_t, xn_t, xsr_t, V_DIM);
        gather_pack_kernel<<<gGat, 256, 0, stream>>>(
            xn_t, srcs + (size_t)t * E_DIM, rowptr + (size_t)t * (V_DIM + 1),
            invdeg + (size_t)t * V_DIM, hb_t, hpack0, t);
        launch_sb(t, hpack0, P0);
        gemm_mixP_kernel<<<dim3(4, gM64), 256, 0, stream>>>(stateR, wmix0p, part, V_DIM);
        reduce4_kernel<<<gRed, 256, 0, stream>>>(part, b_mix0, xsr_t, x1b_t, V_DIM);
        // ---- layer 1 (xsr region only needed at t=7) ----
        gemm_cat3_kernel<8><<<dim3(t == T_DIM - 1 ? 3 : 2, gM64), 256, 0, stream>>>(
            x1b_t, wcat1p, bcat1, hb_t, xn_t, xsr_t, V_DIM);
        gather_pack_kernel<<<gGat, 256, 0, stream>>>(
            xn_t, srcs + (size_t)t * E_DIM, rowptr + (size_t)t * (V_DIM + 1),
            invdeg + (size_t)t * V_DIM, hb_t, hpack1, t);
    }

    // ================= layer-1 mix (t=7 only, closed-form state) =================
    launch_sb(T_DIM - 1, hpack1, P1);
    gemm_mixP_kernel<<<dim3(4, gM64), 256, 0, stream>>>(stateR, wmix1p, part, V_DIM);
    reduce4_kernel<<<gRed, 256, 0, stream>>>(part, b_mix1, xsr_t, out1_b, V_DIM);

    // ================= head =================
    gemm16_kernel<1, 4, false><<<cdiv(V_DIM,32), 512, 0, stream>>>(
        out1_b, woutp, b_out, (float*)d_out, V_DIM, 256);
}

// Round 9
// 1747.453 us; speedup vs baseline: 1.3011x; 1.3011x over previous
//
#include <hip/hip_runtime.h>
#include <cstdint>
#include <cstddef>

#define T_DIM 8
#define V_DIM 10000
#define E_DIM 100000
#define VS (V_DIM * 256)

typedef __attribute__((ext_vector_type(8))) short short8;
typedef __attribute__((ext_vector_type(4))) float floatx4;

__device__ __forceinline__ unsigned int f2bf(float f) {
    union { float f; unsigned int u; } v; v.f = f;
    unsigned int u = v.u;
    u = u + 0x7FFFu + ((u >> 16) & 1u);   // RNE
    return u >> 16;
}
__device__ __forceinline__ float bf2f(unsigned int s) {
    union { unsigned int u; float f; } v; v.u = s << 16;
    return v.f;
}
__device__ __forceinline__ short8 relu8(short8 x) {
    const short8 z = {0,0,0,0,0,0,0,0};
    return __builtin_elementwise_max(x, z);   // v_pk_max_i16: bf16 relu on bit pattern
}
union PK { uint4 u; short8 s; };

// ---- pack fp32 weight [K,Nw] into MFMA B-fragment order inside a concat buffer
__global__ void pack_b_kernel(const float* __restrict__ w, unsigned short* __restrict__ out,
                              int K, int Nw, int NTN_tot, int nt_off) {
    int tid = blockIdx.x * blockDim.x + threadIdx.x;
    int total = (K >> 5) * (Nw >> 4) * 64;
    if (tid >= total) return;
    int lane = tid & 63;
    int f = tid >> 6;
    int ntn_w = Nw >> 4;
    int nt = f % ntn_w;
    int kt = f / ntn_w;
    int kbase = kt * 32 + ((lane >> 4) << 3);
    int n = nt * 16 + (lane & 15);
    unsigned int vals[8];
#pragma unroll
    for (int j = 0; j < 8; ++j)
        vals[j] = f2bf(w[(size_t)(kbase + j) * Nw + n]);
    uint4 pk;
    pk.x = vals[0] | (vals[1] << 16);
    pk.y = vals[2] | (vals[3] << 16);
    pk.z = vals[4] | (vals[5] << 16);
    pk.w = vals[6] | (vals[7] << 16);
    size_t fo = (size_t)kt * NTN_tot + nt_off + nt;
    *(uint4*)(out + (fo * 64 + lane) * 8) = pk;
}

// ---- token mixer ----
__global__ void token_mix_kernel(const float* __restrict__ xs, const float* __restrict__ w_pre,
                                 const float* __restrict__ b_pre, unsigned short* __restrict__ ob) {
    const int S = V_DIM * 128;
    int tid = blockIdx.x * blockDim.x + threadIdx.x;
    if (tid >= T_DIM * S / 4) return;
    int e = tid * 4;
    int t = e / S;
    int c = e & 127;
    floatx4 xm = {0.f,0.f,0.f,0.f}, xp = {0.f,0.f,0.f,0.f};
    floatx4 x0 = *(const floatx4*)(xs + e);
    if (t > 0)          xm = *(const floatx4*)(xs + e - S);
    if (t < T_DIM - 1)  xp = *(const floatx4*)(xs + e + S);
    uint2 p; unsigned int b[4];
#pragma unroll
    for (int j = 0; j < 4; ++j) {
        int cc = c + j;
        float r = xm[j]*w_pre[cc*3+0] + x0[j]*w_pre[cc*3+1] + xp[j]*w_pre[cc*3+2] + b_pre[cc];
        b[j] = f2bf(r);
    }
    p.x = b[0] | (b[1] << 16);
    p.y = b[2] | (b[3] << 16);
    *(uint2*)(ob + e) = p;
}

// ---- P0[d][k] = B0[k]*lam0^d ; P1[d][k] = B1[k]*lam1^d  (d = 0..7) ----
__global__ void lamP_kernel(const float* __restrict__ a0, const float* __restrict__ a1,
                            const float* __restrict__ B0, const float* __restrict__ B1,
                            float* __restrict__ P0, float* __restrict__ P1) {
    int i = blockIdx.x * blockDim.x + threadIdx.x;
    if (i >= 4096) return;
    float l0 = expf(-expf(a0[i]));
    float l1 = expf(-expf(a1[i]));
    float p0 = B0[i], p1 = B1[i];
#pragma unroll
    for (int d = 0; d < 8; ++d) {
        P0[d * 4096 + i] = p0;
        P1[d * 4096 + i] = p1;
        p0 *= l0; p1 *= l1;
    }
}

// ---- bias concat: [b_sage | 0 | b_res] per layer (region order self|neigh|res) ----
__global__ void bias_cat_kernel(const float* __restrict__ br0, const float* __restrict__ bs0,
                                const float* __restrict__ br1, const float* __restrict__ bs1,
                                float* __restrict__ bcat0, float* __restrict__ bcat1) {
    int i = blockIdx.x * blockDim.x + threadIdx.x;
    if (i >= 768) return;
    bcat0[i] = (i < 256) ? bs0[i] : (i < 512 ? 0.f : br0[i - 512]);
    bcat1[i] = (i < 256) ? bs1[i] : (i < 512 ? 0.f : br1[i - 512]);
}

// ================= CSR build =================
__global__ void deg_kernel(const int* __restrict__ ei, int* __restrict__ deg_cnt) {
    int tid = blockIdx.x * blockDim.x + threadIdx.x;
    if (tid >= T_DIM * E_DIM) return;
    int t = tid / E_DIM;
    int e = tid - t * E_DIM;
    int dst = ei[(size_t)t * 2 * E_DIM + E_DIM + e];
    if ((unsigned)dst < V_DIM) atomicAdd(deg_cnt + t * V_DIM + dst, 1);
}

__global__ void invdeg_kernel(const int* __restrict__ deg_cnt, float* __restrict__ inv) {
    int tid = blockIdx.x * blockDim.x + threadIdx.x;
    if (tid >= T_DIM * V_DIM) return;
    inv[tid] = 1.0f / (float)max(deg_cnt[tid], 1);
}

__global__ __launch_bounds__(1024)
void scan_kernel(const int* __restrict__ deg_cnt, int* __restrict__ rowptr) {
    __shared__ int sums[1024];
    int t = blockIdx.x;
    const int* d = deg_cnt + t * V_DIM;
    int* rp = rowptr + t * (V_DIM + 1);
    int tid = threadIdx.x;
    int base = tid * 10;
    int loc[10]; int s = 0;
#pragma unroll
    for (int j = 0; j < 10; ++j) {
        int v = base + j;
        int x = (v < V_DIM) ? d[v] : 0;
        loc[j] = s; s += x;
    }
    sums[tid] = s;
    __syncthreads();
    for (int o = 1; o < 1024; o <<= 1) {
        int v = (tid >= o) ? sums[tid - o] : 0;
        __syncthreads();
        sums[tid] += v;
        __syncthreads();
    }
    int prev = (tid == 0) ? 0 : sums[tid - 1];
#pragma unroll
    for (int j = 0; j < 10; ++j) {
        int v = base + j;
        if (v < V_DIM) rp[v] = prev + loc[j];
    }
    if (tid == 1023) rp[V_DIM] = sums[1023];
}

__global__ void fill_kernel(const int* __restrict__ ei, const int* __restrict__ rowptr,
                            int* __restrict__ fill_cnt, int* __restrict__ srcs) {
    int tid = blockIdx.x * blockDim.x + threadIdx.x;
    if (tid >= T_DIM * E_DIM) return;
    int t = tid / E_DIM;
    int e = tid - t * E_DIM;
    const int* eit = ei + (size_t)t * 2 * E_DIM;
    int src = eit[e];
    int dst = eit[E_DIM + e];
    if ((unsigned)src >= V_DIM || (unsigned)dst >= V_DIM) return;
    int pos = rowptr[t * (V_DIM + 1) + dst] + atomicAdd(fill_cnt + t * V_DIM + dst, 1);
    srcs[(size_t)t * E_DIM + pos] = src;
}

// ---- gather + slot-pack: h = hb + (sum xn[src])*invdeg, written to hpack[v][c][slot]
__global__ void gather_pack_kernel(const unsigned short* __restrict__ xn, const int* __restrict__ srcs,
                                   const int* __restrict__ rowptr, const float* __restrict__ invdeg,
                                   const unsigned short* __restrict__ hb,
                                   unsigned short* __restrict__ hpack, int slot) {
    int gw = (blockIdx.x * blockDim.x + threadIdx.x) >> 6;
    int lane = threadIdx.x & 63;
    if (gw >= V_DIM) return;
    int beg = rowptr[gw], end = rowptr[gw + 1];
    float a0 = 0.f, a1 = 0.f, a2 = 0.f, a3 = 0.f;
    for (int i = beg; i < end; ++i) {
        int s = srcs[i];
        uint2 p = *(const uint2*)(xn + (size_t)s * 256 + lane * 4);
        a0 += bf2f(p.x & 0xffffu);
        a1 += bf2f(p.x >> 16);
        a2 += bf2f(p.y & 0xffffu);
        a3 += bf2f(p.y >> 16);
    }
    float inv = invdeg[gw];
    uint2 h = *(const uint2*)(hb + (size_t)gw * 256 + lane * 4);
    a0 = a0 * inv + bf2f(h.x & 0xffffu);
    a1 = a1 * inv + bf2f(h.x >> 16);
    a2 = a2 * inv + bf2f(h.y & 0xffffu);
    a3 = a3 * inv + bf2f(h.y >> 16);
    unsigned short* op = hpack + (size_t)gw * 2048 + (size_t)(lane * 4) * 8 + slot;
    op[0]  = (unsigned short)f2bf(a0);
    op[8]  = (unsigned short)f2bf(a1);
    op[16] = (unsigned short)f2bf(a2);
    op[24] = (unsigned short)f2bf(a3);
}

// ---- cat GEMM: x(t) @ [w_self|w_neigh|w_res]; region 0->bf16 d_self, 1->bf16 d_xn, 2->f32 d_xsr
template<int KT>
__global__ __launch_bounds__(256, 4)
void gemm_cat3_kernel(const unsigned short* __restrict__ A, const unsigned short* __restrict__ Bp,
                      const float* __restrict__ bias, unsigned short* __restrict__ d_self,
                      unsigned short* __restrict__ d_xn, float* __restrict__ d_xsr, int M) {
    const int w = threadIdx.x >> 6, lane = threadIdx.x & 63;
    const int quad = lane >> 4, l16 = lane & 15;
    const int region = blockIdx.x;
    const int m0 = blockIdx.y * 64;
    constexpr int K = KT * 32;
    floatx4 acc[4][4];
#pragma unroll
    for (int a = 0; a < 4; ++a)
#pragma unroll
        for (int b = 0; b < 4; ++b) acc[a][b] = (floatx4){0.f,0.f,0.f,0.f};
    const unsigned short* arow[4];
#pragma unroll
    for (int mi = 0; mi < 4; ++mi) {
        int r = m0 + mi * 16 + l16;
        if (r > M - 1) r = M - 1;
        arow[mi] = A + (size_t)r * K + quad * 8;
    }
    const unsigned short* bptr = Bp + ((size_t)(region * 16 + w * 4) * 64 + lane) * 8;
#pragma unroll
    for (int kt = 0; kt < KT; ++kt) {
        short8 bfr[4];
#pragma unroll
        for (int i = 0; i < 4; ++i) bfr[i] = *(const short8*)(bptr + i * 512);
        short8 af[4];
#pragma unroll
        for (int mi = 0; mi < 4; ++mi) af[mi] = *(const short8*)(arow[mi]);
#pragma unroll
        for (int mi = 0; mi < 4; ++mi)
#pragma unroll
            for (int i = 0; i < 4; ++i)
                acc[mi][i] = __builtin_amdgcn_mfma_f32_16x16x32_bf16(af[mi], bfr[i], acc[mi][i], 0, 0, 0);
        bptr += 48 * 512;
#pragma unroll
        for (int mi = 0; mi < 4; ++mi) arow[mi] += 32;
    }
#pragma unroll
    for (int mi = 0; mi < 4; ++mi) {
        int rbase = m0 + mi * 16 + quad * 4;
#pragma unroll
        for (int i = 0; i < 4; ++i) {
            int lcol = w * 64 + i * 16 + l16;
            float b = bias[region * 256 + lcol];
#pragma unroll
            for (int rr = 0; rr < 4; ++rr) {
                int row = rbase + rr;
                if (row < M) {
                    float v = acc[mi][i][rr] + b;
                    size_t off = (size_t)row * 256 + lcol;
                    if (region == 0) d_self[off] = (unsigned short)f2bf(v);
                    else if (region == 1) d_xn[off] = (unsigned short)f2bf(v);
                    else d_xsr[off] = v;
                }
            }
        }
    }
}

// ---- fused closed-form SSM + split-K(8) mix GEMM, slot-packed h, P in LDS ----
// split ks owns k range [ks*512, ks*512+512) = 16 kt. P slice staged in LDS.
// state[v,k] = sum_{tau<=TT} P[TT-tau][k]*h[tau][v][k>>4]; bf16-round once; relu -> MFMA.
template<int TT>
__global__ __launch_bounds__(256)
void gemm_mix_cf3_kernel(const unsigned short* __restrict__ hp,   // [V][256][8]
                         const unsigned short* __restrict__ Bp,   // packed w_mix
                         const float* __restrict__ P,             // [8][4096]
                         float* __restrict__ part, int M) {
    __shared__ float Pl[(TT + 1) * 512];
    const int w = threadIdx.x >> 6, lane = threadIdx.x & 63;
    const int quad = lane >> 4, l16 = lane & 15;
    const int ks = blockIdx.x;           // 0..7
    const int m0 = blockIdx.y * 64;
    // stage P slice -> LDS (16B per thread per iter)
    for (int i = threadIdx.x * 4; i < (TT + 1) * 512; i += 1024) {
        int d = i >> 9;
        int kk = i & 511;
        *(floatx4*)(Pl + i) = *(const floatx4*)(P + (size_t)d * 4096 + ks * 512 + kk);
    }
    __syncthreads();
    floatx4 acc[4][4];
#pragma unroll
    for (int a = 0; a < 4; ++a)
#pragma unroll
        for (int b = 0; b < 4; ++b) acc[a][b] = (floatx4){0.f,0.f,0.f,0.f};
    const unsigned short* hrow[4];
#pragma unroll
    for (int mi = 0; mi < 4; ++mi) {
        int r = m0 + mi * 16 + l16;
        if (r > M - 1) r = M - 1;
        hrow[mi] = hp + (size_t)r * 2048;
    }
    const unsigned short* bptr = Bp + ((size_t)(ks * 256 + w * 4) * 64 + lane) * 8;
    for (int kt = 0; kt < 16; ++kt) {
        const int kloc = kt * 32 + quad * 8;       // within slice
        const int hh = (ks * 512 + kloc) >> 4;
        short8 bfr[4];
#pragma unroll
        for (int i = 0; i < 4; ++i) bfr[i] = *(const short8*)(bptr + i * 512);
        PK h8[4];
#pragma unroll
        for (int mi = 0; mi < 4; ++mi) h8[mi].u = *(const uint4*)(hrow[mi] + hh * 8);
        float sv[4][8];
#pragma unroll
        for (int mi = 0; mi < 4; ++mi)
#pragma unroll
            for (int j = 0; j < 8; ++j) sv[mi][j] = 0.f;
#pragma unroll
        for (int tau = 0; tau <= TT; ++tau) {
            const float* Pd = Pl + (TT - tau) * 512 + kloc;
            floatx4 p0 = *(const floatx4*)Pd;
            floatx4 p1 = *(const floatx4*)(Pd + 4);
#pragma unroll
            for (int mi = 0; mi < 4; ++mi) {
                float hv = bf2f((unsigned int)(unsigned short)h8[mi].s[tau]);
#pragma unroll
                for (int j = 0; j < 4; ++j) {
                    sv[mi][j]   += hv * p0[j];
                    sv[mi][4+j] += hv * p1[j];
                }
            }
        }
        short8 af[4];
#pragma unroll
        for (int mi = 0; mi < 4; ++mi) {
            PK cv;
            cv.u.x = f2bf(sv[mi][0]) | (f2bf(sv[mi][1]) << 16);
            cv.u.y = f2bf(sv[mi][2]) | (f2bf(sv[mi][3]) << 16);
            cv.u.z = f2bf(sv[mi][4]) | (f2bf(sv[mi][5]) << 16);
            cv.u.w = f2bf(sv[mi][6]) | (f2bf(sv[mi][7]) << 16);
            af[mi] = relu8(cv.s);
        }
#pragma unroll
        for (int mi = 0; mi < 4; ++mi)
#pragma unroll
            for (int i = 0; i < 4; ++i)
                acc[mi][i] = __builtin_amdgcn_mfma_f32_16x16x32_bf16(af[mi], bfr[i], acc[mi][i], 0, 0, 0);
        bptr += 16 * 512;
    }
#pragma unroll
    for (int mi = 0; mi < 4; ++mi) {
        int rbase = m0 + mi * 16 + quad * 4;
#pragma unroll
        for (int i = 0; i < 4; ++i) {
            int col = w * 64 + i * 16 + l16;
#pragma unroll
            for (int rr = 0; rr < 4; ++rr) {
                int row = rbase + rr;
                if (row < M)
                    part[((size_t)ks * M + row) * 256 + col] = acc[mi][i][rr];
            }
        }
    }
}

// ---- reduce 8 split-K partials + bias + resid -> bf16 ----
__global__ void reduce8_kernel(const float* __restrict__ part, const float* __restrict__ bias,
                               const float* __restrict__ resid, unsigned short* __restrict__ out, int M) {
    int tid = blockIdx.x * blockDim.x + threadIdx.x;
    if (tid >= M * 64) return;
    size_t i4 = (size_t)tid * 4;
    const size_t S = (size_t)M * 256;
    floatx4 rv = *(const floatx4*)(resid + i4);
    floatx4 bv = *(const floatx4*)(bias + (i4 & 255));
    float v0 = rv[0] + bv[0], v1 = rv[1] + bv[1], v2 = rv[2] + bv[2], v3 = rv[3] + bv[3];
#pragma unroll
    for (int s = 0; s < 8; ++s) {
        floatx4 p = *(const floatx4*)(part + (size_t)s * S + i4);
        v0 += p[0]; v1 += p[1]; v2 += p[2]; v3 += p[3];
    }
    uint2 o;
    o.x = f2bf(v0) | (f2bf(v1) << 16);
    o.y = f2bf(v2) | (f2bf(v3) << 16);
    *(uint2*)(out + i4) = o;
}

// ---- small GEMM (head): 32-row blocks, 8 waves ----
template<int NT, int NTN_TOT, bool RELU>
__global__ __launch_bounds__(512)
void gemm16_kernel(const unsigned short* __restrict__ A, const unsigned short* __restrict__ Bp,
                   const float* __restrict__ bias, float* __restrict__ outF, int M, int K) {
    const int w = threadIdx.x >> 6, lane = threadIdx.x & 63;
    const int quad = lane >> 4, l16 = lane & 15;
    const int rowgrp = w >> 2, nchunk = w & 3;
    const int m0 = blockIdx.x * 32 + rowgrp * 16;
    const int ntb = nchunk * NT;
    constexpr int Ntot = NTN_TOT * 16;
    floatx4 acc[NT];
#pragma unroll
    for (int i = 0; i < NT; ++i) acc[i] = (floatx4){0.f,0.f,0.f,0.f};
    int r = m0 + l16; if (r > M - 1) r = M - 1;
    const unsigned short* arow = A + (size_t)r * K + quad * 8;
    const int ksteps = K >> 5;
    for (int kt = 0; kt < ksteps; ++kt) {
        short8 af = *(const short8*)(arow + kt * 32);
        if (RELU) af = relu8(af);
#pragma unroll
        for (int i = 0; i < NT; ++i) {
            short8 bf = *(const short8*)(Bp + ((size_t)(kt * NTN_TOT + ntb + i) * 64 + lane) * 8);
            acc[i] = __builtin_amdgcn_mfma_f32_16x16x32_bf16(af, bf, acc[i], 0, 0, 0);
        }
    }
    const int rbase = m0 + quad * 4;
#pragma unroll
    for (int i = 0; i < NT; ++i) {
        int col = (ntb + i) * 16 + l16;
        float b = bias[col];
#pragma unroll
        for (int rr = 0; rr < 4; ++rr) {
            int row = rbase + rr;
            if (row < M)
                outF[(size_t)row * Ntot + col] = acc[i][rr] + b;
        }
    }
}

extern "C" void kernel_launch(void* const* d_in, const int* in_sizes, int n_in,
                              void* d_out, int out_size, void* d_ws, size_t ws_size,
                              hipStream_t stream) {
    const float* xs      = (const float*)d_in[0];
    const int*   ei      = (const int*)d_in[1];
    const float* w_pre   = (const float*)d_in[2];
    const float* b_pre   = (const float*)d_in[3];
    const float* w_res0  = (const float*)d_in[4];
    const float* b_res0  = (const float*)d_in[5];
    const float* w_self0 = (const float*)d_in[6];
    const float* w_neigh0= (const float*)d_in[7];
    const float* b_sage0 = (const float*)d_in[8];
    const float* a_log0  = (const float*)d_in[9];
    const float* B0      = (const float*)d_in[10];
    const float* w_mix0  = (const float*)d_in[11];
    const float* b_mix0  = (const float*)d_in[12];
    const float* w_res1  = (const float*)d_in[13];
    const float* b_res1  = (const float*)d_in[14];
    const float* w_self1 = (const float*)d_in[15];
    const float* w_neigh1= (const float*)d_in[16];
    const float* b_sage1 = (const float*)d_in[17];
    const float* a_log1  = (const float*)d_in[18];
    const float* B1      = (const float*)d_in[19];
    const float* w_mix1  = (const float*)d_in[20];
    const float* b_mix1  = (const float*)d_in[21];
    const float* w_out   = (const float*)d_in[22];
    const float* b_out   = (const float*)d_in[23];

    char* wsB = (char*)d_ws;
    size_t off = 0;
    auto alloc = [&](size_t bytes) {
        char* p = wsB + off;
        off += (bytes + 255) & ~(size_t)255;
        return p;
    };
    unsigned short* x0b   = (unsigned short*)alloc((size_t)T_DIM * V_DIM * 128 * 2);
    unsigned short* hpack0= (unsigned short*)alloc((size_t)V_DIM * 2048 * 2);   // [V][256][8] layer-0 h
    unsigned short* hpack1= (unsigned short*)alloc((size_t)V_DIM * 2048 * 2);   // [V][256][8] layer-1 h
    unsigned short* hb_t  = (unsigned short*)alloc((size_t)VS * 2);
    unsigned short* x1b_t = (unsigned short*)alloc((size_t)VS * 2);
    unsigned short* xn_t  = (unsigned short*)alloc((size_t)VS * 2);
    float*          xsr_t = (float*)alloc((size_t)VS * 4);
    float*          part  = (float*)alloc((size_t)8 * VS * 4);
    unsigned short* out1_b= (unsigned short*)alloc((size_t)VS * 2);
    int*            deg_cnt = (int*)alloc((size_t)T_DIM * V_DIM * 4);
    float*          invdeg  = (float*)alloc((size_t)T_DIM * V_DIM * 4);
    int*            rowptr  = (int*)alloc((size_t)T_DIM * (V_DIM + 1) * 4);
    int*            fill_cnt= (int*)alloc((size_t)T_DIM * V_DIM * 4);
    int*            srcs    = (int*)alloc((size_t)T_DIM * E_DIM * 4);
    float*          P0    = (float*)alloc(8 * 4096 * 4);
    float*          P1    = (float*)alloc(8 * 4096 * 4);
    float*          bcat0 = (float*)alloc(768 * 4);
    float*          bcat1 = (float*)alloc(768 * 4);
    unsigned short* wcat0p= (unsigned short*)alloc((size_t)128 * 768 * 2);
    unsigned short* wcat1p= (unsigned short*)alloc((size_t)256 * 768 * 2);
    unsigned short* wmix0p= (unsigned short*)alloc((size_t)4096 * 256 * 2);
    unsigned short* wmix1p= (unsigned short*)alloc((size_t)4096 * 256 * 2);
    unsigned short* woutp = (unsigned short*)alloc((size_t)256 * 64 * 2);
    if (off > ws_size) return;   // fail cleanly, not a GPU fault

    auto cdiv = [](int a, int b) { return (a + b - 1) / b; };
    const int gM64 = cdiv(V_DIM, 64);    // 157
    const int gGat = cdiv(V_DIM * 64, 256);
    const int gRed = cdiv(V_DIM * 64, 256);

    auto launch_mix = [&](int t, const unsigned short* hp, const unsigned short* wp,
                          const float* P) {
        dim3 g(8, gM64);
        switch (t) {
        case 0: gemm_mix_cf3_kernel<0><<<g, 256, 0, stream>>>(hp, wp, P, part, V_DIM); break;
        case 1: gemm_mix_cf3_kernel<1><<<g, 256, 0, stream>>>(hp, wp, P, part, V_DIM); break;
        case 2: gemm_mix_cf3_kernel<2><<<g, 256, 0, stream>>>(hp, wp, P, part, V_DIM); break;
        case 3: gemm_mix_cf3_kernel<3><<<g, 256, 0, stream>>>(hp, wp, P, part, V_DIM); break;
        case 4: gemm_mix_cf3_kernel<4><<<g, 256, 0, stream>>>(hp, wp, P, part, V_DIM); break;
        case 5: gemm_mix_cf3_kernel<5><<<g, 256, 0, stream>>>(hp, wp, P, part, V_DIM); break;
        case 6: gemm_mix_cf3_kernel<6><<<g, 256, 0, stream>>>(hp, wp, P, part, V_DIM); break;
        default: gemm_mix_cf3_kernel<7><<<g, 256, 0, stream>>>(hp, wp, P, part, V_DIM); break;
        }
    };

    // ---- parameter prep ----
    lamP_kernel<<<16, 256, 0, stream>>>(a_log0, a_log1, B0, B1, P0, P1);
    bias_cat_kernel<<<3, 256, 0, stream>>>(b_res0, b_sage0, b_res1, b_sage1, bcat0, bcat1);
    // region order: [self | neigh | res]
    pack_b_kernel<<<cdiv(4*16*64, 256), 256, 0, stream>>>(w_self0,  wcat0p, 128, 256, 48, 0);
    pack_b_kernel<<<cdiv(4*16*64, 256), 256, 0, stream>>>(w_neigh0, wcat0p, 128, 256, 48, 16);
    pack_b_kernel<<<cdiv(4*16*64, 256), 256, 0, stream>>>(w_res0,   wcat0p, 128, 256, 48, 32);
    pack_b_kernel<<<cdiv(8*16*64, 256), 256, 0, stream>>>(w_self1,  wcat1p, 256, 256, 48, 0);
    pack_b_kernel<<<cdiv(8*16*64, 256), 256, 0, stream>>>(w_neigh1, wcat1p, 256, 256, 48, 16);
    pack_b_kernel<<<cdiv(8*16*64, 256), 256, 0, stream>>>(w_res1,   wcat1p, 256, 256, 48, 32);
    pack_b_kernel<<<cdiv(128*16*64, 256), 256, 0, stream>>>(w_mix0, wmix0p, 4096, 256, 16, 0);
    pack_b_kernel<<<cdiv(128*16*64, 256), 256, 0, stream>>>(w_mix1, wmix1p, 4096, 256, 16, 0);
    pack_b_kernel<<<cdiv(8*4*64, 256), 256, 0, stream>>>(w_out, woutp, 256, 64, 4, 0);

    // ---- token mixer + CSR build ----
    token_mix_kernel<<<cdiv(T_DIM*V_DIM*128/4, 256), 256, 0, stream>>>(xs, w_pre, b_pre, x0b);
    hipMemsetAsync(deg_cnt, 0, (size_t)T_DIM * V_DIM * 4, stream);
    hipMemsetAsync(fill_cnt, 0, (size_t)T_DIM * V_DIM * 4, stream);
    deg_kernel<<<cdiv(T_DIM*E_DIM, 256), 256, 0, stream>>>(ei, deg_cnt);
    scan_kernel<<<T_DIM, 1024, 0, stream>>>(deg_cnt, rowptr);
    invdeg_kernel<<<cdiv(T_DIM*V_DIM, 256), 256, 0, stream>>>(deg_cnt, invdeg);
    fill_kernel<<<cdiv(T_DIM*E_DIM, 256), 256, 0, stream>>>(ei, rowptr, fill_cnt, srcs);

    // ================= main loop over t =================
    for (int t = 0; t < T_DIM; ++t) {
        // ---- layer 0 ----
        gemm_cat3_kernel<4><<<dim3(3, gM64), 256, 0, stream>>>(
            x0b + (size_t)t * V_DIM * 128, wcat0p, bcat0, hb_t, xn_t, xsr_t, V_DIM);
        gather_pack_kernel<<<gGat, 256, 0, stream>>>(
            xn_t, srcs + (size_t)t * E_DIM, rowptr + (size_t)t * (V_DIM + 1),
            invdeg + (size_t)t * V_DIM, hb_t, hpack0, t);
        launch_mix(t, hpack0, wmix0p, P0);
        reduce8_kernel<<<gRed, 256, 0, stream>>>(part, b_mix0, xsr_t, x1b_t, V_DIM);
        // ---- layer 1 (xsr region only needed at t=7) ----
        gemm_cat3_kernel<8><<<dim3(t == T_DIM - 1 ? 3 : 2, gM64), 256, 0, stream>>>(
            x1b_t, wcat1p, bcat1, hb_t, xn_t, xsr_t, V_DIM);
        gather_pack_kernel<<<gGat, 256, 0, stream>>>(
            xn_t, srcs + (size_t)t * E_DIM, rowptr + (size_t)t * (V_DIM + 1),
            invdeg + (size_t)t * V_DIM, hb_t, hpack1, t);
    }

    // ================= layer-1 mix (t=7 only, closed-form state) =================
    launch_mix(T_DIM - 1, hpack1, wmix1p, P1);
    reduce8_kernel<<<gRed, 256, 0, stream>>>(part, b_mix1, xsr_t, out1_b, V_DIM);

    // ================= head =================
    gemm16_kernel<1, 4, false><<<cdiv(V_DIM,32), 512, 0, stream>>>(
        out1_b, woutp, b_out, (float*)d_out, V_DIM, 256);
}